// Round 4
// baseline (344.392 us; speedup 1.0000x reference)
//
#include <hip/hip_runtime.h>
#include <hip/hip_cooperative_groups.h>
#include <math.h>

namespace cg = cooperative_groups;

#define BS 640
#define IN_CH 2048
#define NGRP 174
#define OUT_CH 696
#define CHUNK 320
#define EPS_BN 1e-5f
#define LOG2E 1.4426950408889634f

#define NBLK 512
#define NTHR 256

#if __has_builtin(__builtin_amdgcn_exp2f)
#define EXP2(x) __builtin_amdgcn_exp2f(x)
#else
#define EXP2(x) exp2f(x)
#endif

typedef short short8 __attribute__((ext_vector_type(8)));
typedef float f32x4 __attribute__((ext_vector_type(4)));

__device__ inline unsigned short bf16_rne(float x) {
    unsigned int u = __float_as_uint(x);
    return (unsigned short)((u + 0x7FFFu + ((u >> 16) & 1u)) >> 16);
}
__device__ inline float blo(unsigned int u) { return __uint_as_float(u << 16); }
__device__ inline float bhi(unsigned int u) { return __uint_as_float(u & 0xFFFF0000u); }

union SMem {
    struct { unsigned short Ah[32 * 64], Al[32 * 64], Bh[32 * 64], Bl[32 * 64]; } g; // 16 KB
    struct { uint4 kv[4][BS]; } a;                                                  // 40 KB
};

__global__ __launch_bounds__(NTHR, 2) void mega(
        const float* __restrict__ X, const float* __restrict__ prior,
        const float* __restrict__ W,
        const float* __restrict__ gamma, const float* __restrict__ beta,
        const float* __restrict__ ipw, const float* __restrict__ ipb,
        const float* __restrict__ opw, const float* __restrict__ opb,
        float* __restrict__ H, float* __restrict__ stats) {
    __shared__ SMem sm;
    cg::grid_group grid = cg::this_grid();
    const int bid = blockIdx.x, tid = threadIdx.x;
    const int lane = tid & 63, wv = tid >> 6;

    // ================= phase 1: GEMM  H = X @ W^T (split-bf16 MFMA) =============
    // 440 tiles of 32x32, BK=64, 4 waves: wave w -> (rowhalf, colhalf) 16x16 frag.
    if (bid < 440) {
        int row0 = (bid % 20) * 32;
        int col0 = (bid / 20) * 32;
        int rowh = wv >> 1, colh = wv & 1;
        int lr = lane & 15, lq = lane >> 4;
        f32x4 acc = {};
        for (int kt = 0; kt < 32; ++kt) {
            __syncthreads();
#pragma unroll
            for (int i = 0; i < 2; ++i) {               // A then B staging, 2 f4 each
                int idx = tid + i * 256;
                int r = idx >> 4;                        // 0..31
                int kc = (idx & 15) * 4;                 // 0..60 step 4
                float4 va = *(const float4*)(X + (size_t)(row0 + r) * IN_CH + kt * 64 + kc);
                int wrow = col0 + r; if (wrow > OUT_CH - 1) wrow = OUT_CH - 1;
                float4 vb = *(const float4*)(W + (size_t)wrow * IN_CH + kt * 64 + kc);
                int ci = kc >> 3, half = (kc >> 2) & 1;
                int off = r * 64 + ((ci ^ (r & 7)) << 3) + half * 4;
                float fa[4] = {va.x, va.y, va.z, va.w};
                float fb[4] = {vb.x, vb.y, vb.z, vb.w};
                unsigned short ah[4], al[4], bh[4], bl[4];
#pragma unroll
                for (int j = 0; j < 4; ++j) {
                    ah[j] = bf16_rne(fa[j]);
                    al[j] = bf16_rne(fa[j] - __uint_as_float(((unsigned int)ah[j]) << 16));
                    bh[j] = bf16_rne(fb[j]);
                    bl[j] = bf16_rne(fb[j] - __uint_as_float(((unsigned int)bh[j]) << 16));
                }
                *(ushort4*)&sm.g.Ah[off] = make_ushort4(ah[0], ah[1], ah[2], ah[3]);
                *(ushort4*)&sm.g.Al[off] = make_ushort4(al[0], al[1], al[2], al[3]);
                *(ushort4*)&sm.g.Bh[off] = make_ushort4(bh[0], bh[1], bh[2], bh[3]);
                *(ushort4*)&sm.g.Bl[off] = make_ushort4(bl[0], bl[1], bl[2], bl[3]);
            }
            __syncthreads();
#pragma unroll
            for (int kk2 = 0; kk2 < 2; ++kk2) {
                int ci = kk2 * 4 + lq;
                int rA = rowh * 16 + lr;
                int offA = rA * 64 + ((ci ^ (rA & 7)) << 3);
                int rB = colh * 16 + lr;
                int offB = rB * 64 + ((ci ^ (rB & 7)) << 3);
                short8 ah = *(const short8*)&sm.g.Ah[offA];
                short8 al = *(const short8*)&sm.g.Al[offA];
                short8 bh = *(const short8*)&sm.g.Bh[offB];
                short8 bl = *(const short8*)&sm.g.Bl[offB];
                acc = __builtin_amdgcn_mfma_f32_16x16x32_bf16(ah, bh, acc, 0, 0, 0);
                acc = __builtin_amdgcn_mfma_f32_16x16x32_bf16(ah, bl, acc, 0, 0, 0);
                acc = __builtin_amdgcn_mfma_f32_16x16x32_bf16(al, bh, acc, 0, 0, 0);
            }
        }
#pragma unroll
        for (int j = 0; j < 4; ++j) {
            int r = row0 + rowh * 16 + lq * 4 + j;
            int c = col0 + colh * 16 + lr;
            if (c < OUT_CH) H[(size_t)r * OUT_CH + c] = acc[j];
        }
    }
    grid.sync();

    // ================= phase 2: GhostBN folded scale/shift (wave per job) =======
    {
        int j = bid * 4 + wv;
        if (j < 2 * NGRP) {
            int n = j % NGRP, chunk = j / NGRP;
            const float* Hp = H + (size_t)(chunk * CHUNK) * OUT_CH + n * 4;
            float s[4] = {0.f, 0.f, 0.f, 0.f}, qs[4] = {0.f, 0.f, 0.f, 0.f};
            for (int rr = lane; rr < CHUNK; rr += 64) {
                float4 h = *(const float4*)(Hp + (size_t)rr * OUT_CH);
                float hv[4] = {h.x, h.y, h.z, h.w};
#pragma unroll
                for (int e = 0; e < 4; ++e) { s[e] += hv[e]; qs[e] += hv[e] * hv[e]; }
            }
#pragma unroll
            for (int d = 32; d > 0; d >>= 1)
#pragma unroll
                for (int e = 0; e < 4; ++e) {
                    s[e] += __shfl_xor(s[e], d);
                    qs[e] += __shfl_xor(qs[e], d);
                }
            if (lane < 4) {
                int e = lane;
                float m = s[e] * (1.0f / CHUNK);
                float var = qs[e] * (1.0f / CHUNK) - m * m;
                float scv = rsqrtf(var + EPS_BN) * gamma[n * 4 + e];
                stats[j * 8 + e] = scv;
                stats[j * 8 + 4 + e] = beta[n * 4 + e] - m * scv;
            }
        }
    }
    grid.sync();

    // ================= phase 3: attention (wave per 64-query job) ===============
    {
        int job = bid * 4 + wv;
        bool ok = job < NGRP * 10;
        int n = ok ? job / 10 : 0;
        int qb = ok ? job % 10 : 0;
        int c0 = n * 4;
        if (ok) {   // stage packed bf16 kv: physical t holds s=(t&3)*160+(t>>2)
            for (int t = lane; t < BS; t += 64) {
                int s = (t & 3) * 160 + (t >> 2);
                float4 pr = *(const float4*)(prior + (size_t)s * OUT_CH + c0);
                float p_[4] = {pr.x, pr.y, pr.z, pr.w};
                float kk[4], vvv[4];
#pragma unroll
                for (int e = 0; e < 4; ++e) {
                    float ak = ipb[4 + e], av = ipb[8 + e];
#pragma unroll
                    for (int e2 = 0; e2 < 4; ++e2) {
                        ak = fmaf(ipw[(4 + e) * 4 + e2], p_[e2], ak);
                        av = fmaf(ipw[(8 + e) * 4 + e2], p_[e2], av);
                    }
                    kk[e] = ak; vvv[e] = av;
                }
                unsigned int u0 = (unsigned int)bf16_rne(kk[0]) | ((unsigned int)bf16_rne(kk[1]) << 16);
                unsigned int u1 = (unsigned int)bf16_rne(kk[2]) | ((unsigned int)bf16_rne(kk[3]) << 16);
                unsigned int u2 = (unsigned int)bf16_rne(vvv[0]) | ((unsigned int)bf16_rne(vvv[1]) << 16);
                unsigned int u3 = (unsigned int)bf16_rne(vvv[2]) | ((unsigned int)bf16_rne(vvv[3]) << 16);
                sm.a.kv[wv][t] = make_uint4(u0, u1, u2, u3);
            }
        }
        __syncthreads();
        if (ok) {
            // ---- k extrema (linear scan, full-wave reduce) ----
            float kmax[4] = {-3e38f, -3e38f, -3e38f, -3e38f};
            float kmin[4] = {3e38f, 3e38f, 3e38f, 3e38f};
            for (int t = lane; t < BS; t += 64) {
                uint4 u = sm.a.kv[wv][t];
                float k_[4] = {blo(u.x), bhi(u.x), blo(u.y), bhi(u.y)};
#pragma unroll
                for (int e = 0; e < 4; ++e) {
                    kmax[e] = fmaxf(kmax[e], k_[e]);
                    kmin[e] = fminf(kmin[e], k_[e]);
                }
            }
#pragma unroll
            for (int d = 32; d > 0; d >>= 1)
#pragma unroll
                for (int e = 0; e < 4; ++e) {
                    kmax[e] = fmaxf(kmax[e], __shfl_xor(kmax[e], d));
                    kmin[e] = fminf(kmin[e], __shfl_xor(kmin[e], d));
                }
            // ---- per-thread: 4 queries, seg quarter of s ----
            int qquad = lane >> 2, seg = lane & 3;
            int q0 = qb * 64 + qquad * 4;
            int chunk = qb >= 5;
            float4 sc4 = *(const float4*)&stats[(chunk * NGRP + n) * 8];
            float4 sh4 = *(const float4*)&stats[(chunk * NGRP + n) * 8 + 4];
            float scv[4] = {sc4.x, sc4.y, sc4.z, sc4.w};
            float shv[4] = {sh4.x, sh4.y, sh4.z, sh4.w};
            float q2v[16], ntm[16], hhk[16];
#pragma unroll
            for (int qq = 0; qq < 4; ++qq) {
                float4 h4 = *(const float4*)(H + (size_t)(q0 + qq) * OUT_CH + c0);
                float4 p4 = *(const float4*)(prior + (size_t)(q0 + qq) * OUT_CH + c0);
                float hr[4] = {h4.x, h4.y, h4.z, h4.w};
                float pq[4] = {p4.x, p4.y, p4.z, p4.w};
                float hh[4];
#pragma unroll
                for (int e = 0; e < 4; ++e) {
                    hh[e] = fmaf(hr[e], scv[e], shv[e]) * pq[e];
                    hhk[qq * 4 + e] = hh[e];
                }
#pragma unroll
                for (int e = 0; e < 4; ++e) {
                    float qv = ipb[e];
#pragma unroll
                    for (int e2 = 0; e2 < 4; ++e2) qv = fmaf(ipw[e * 4 + e2], hh[e2], qv);
                    float q2 = qv * LOG2E;
                    q2v[qq * 4 + e] = q2;
                    ntm[qq * 4 + e] = -((q2 > 0.f) ? q2 * kmax[e] : q2 * kmin[e]);
                }
            }
            float ssum[16], sacc[16];
#pragma unroll
            for (int t2 = 0; t2 < 16; ++t2) { ssum[t2] = 0.f; sacc[t2] = 0.f; }
            const uint4* kvp = &sm.a.kv[wv][seg];
#pragma unroll 2
            for (int i = 0; i < 160; ++i) {
                uint4 u = kvp[(size_t)i * 4];
                float k0 = blo(u.x), k1 = bhi(u.x), k2 = blo(u.y), k3 = bhi(u.y);
                float v0 = blo(u.z), v1 = bhi(u.z), v2 = blo(u.w), v3 = bhi(u.w);
#pragma unroll
                for (int qq = 0; qq < 4; ++qq) {
                    float w0 = EXP2(fmaf(q2v[qq * 4 + 0], k0, ntm[qq * 4 + 0]));
                    float w1 = EXP2(fmaf(q2v[qq * 4 + 1], k1, ntm[qq * 4 + 1]));
                    float w2 = EXP2(fmaf(q2v[qq * 4 + 2], k2, ntm[qq * 4 + 2]));
                    float w3 = EXP2(fmaf(q2v[qq * 4 + 3], k3, ntm[qq * 4 + 3]));
                    ssum[qq * 4 + 0] += w0; sacc[qq * 4 + 0] = fmaf(w0, v0, sacc[qq * 4 + 0]);
                    ssum[qq * 4 + 1] += w1; sacc[qq * 4 + 1] = fmaf(w1, v1, sacc[qq * 4 + 1]);
                    ssum[qq * 4 + 2] += w2; sacc[qq * 4 + 2] = fmaf(w2, v2, sacc[qq * 4 + 2]);
                    ssum[qq * 4 + 3] += w3; sacc[qq * 4 + 3] = fmaf(w3, v3, sacc[qq * 4 + 3]);
                }
            }
#pragma unroll
            for (int d = 1; d < 4; d <<= 1)
#pragma unroll
                for (int t2 = 0; t2 < 16; ++t2) {
                    ssum[t2] += __shfl_xor(ssum[t2], d);
                    sacc[t2] += __shfl_xor(sacc[t2], d);
                }
            if (seg == 0) {
#pragma unroll
                for (int qq = 0; qq < 4; ++qq) {
                    float o[4], y[4];
#pragma unroll
                    for (int e = 0; e < 4; ++e) o[e] = sacc[qq * 4 + e] / ssum[qq * 4 + e];
#pragma unroll
                    for (int e = 0; e < 4; ++e) {
                        float a = opb[e];
#pragma unroll
                        for (int e2 = 0; e2 < 4; ++e2) a = fmaf(opw[e * 4 + e2], o[e2], a);
                        y[e] = a;
                    }
                    *(float4*)(H + (size_t)(q0 + qq) * OUT_CH + c0) =
                        make_float4(hhk[qq * 4 + 0] + y[0], hhk[qq * 4 + 1] + y[1],
                                    hhk[qq * 4 + 2] + y[2], hhk[qq * 4 + 3] + y[3]);
                }
            }
        }
    }
    grid.sync();

    // ================= phase 4: final row softmax (wave per row) ================
    {
        int row = bid * 4 + wv;
        if (row < BS) {
            float* p = H + (size_t)row * OUT_CH;
            float v[11];
#pragma unroll
            for (int i = 0; i < 11; ++i) {
                int c = lane + i * 64;
                v[i] = (c < OUT_CH) ? p[c] : -3e38f;
            }
            float mx = v[0];
#pragma unroll
            for (int i = 1; i < 11; ++i) mx = fmaxf(mx, v[i]);
#pragma unroll
            for (int d = 32; d > 0; d >>= 1) mx = fmaxf(mx, __shfl_xor(mx, d));
            float sum = 0.f;
#pragma unroll
            for (int i = 0; i < 11; ++i) {
                int c = lane + i * 64;
                if (c < OUT_CH) { v[i] = EXP2((v[i] - mx) * LOG2E); sum += v[i]; }
            }
#pragma unroll
            for (int d = 32; d > 0; d >>= 1) sum += __shfl_xor(sum, d);
            float inv = 1.0f / sum;
#pragma unroll
            for (int i = 0; i < 11; ++i) {
                int c = lane + i * 64;
                if (c < OUT_CH) p[c] = v[i] * inv;
            }
        }
    }
}

extern "C" void kernel_launch(void* const* d_in, const int* in_sizes, int n_in,
                              void* d_out, int out_size, void* d_ws, size_t ws_size,
                              hipStream_t stream) {
    const float* x     = (const float*)d_in[0];
    const float* prior = (const float*)d_in[1];
    const float* w_lin = (const float*)d_in[2];
    const float* gamma = (const float*)d_in[3];
    const float* beta  = (const float*)d_in[4];
    const float* ipw   = (const float*)d_in[5];
    const float* ipb   = (const float*)d_in[6];
    const float* opw   = (const float*)d_in[7];
    const float* opb   = (const float*)d_in[8];
    float* out   = (float*)d_out;
    float* stats = (float*)d_ws;   // 2*174*8*4 = 11136 B (same as proven round-2 use)

    void* args[] = {(void*)&x, (void*)&prior, (void*)&w_lin, (void*)&gamma, (void*)&beta,
                    (void*)&ipw, (void*)&ipb, (void*)&opw, (void*)&opb,
                    (void*)&out, (void*)&stats};
    hipLaunchCooperativeKernel((void*)mega, dim3(NBLK), dim3(NTHR), args, 0, stream);
}

// Round 6
// 157.888 us; speedup vs baseline: 2.1812x; 2.1812x over previous
//
#include <hip/hip_runtime.h>
#include <math.h>

#define BS 640
#define IN_CH 2048
#define NGRP 174
#define OUT_CH 696
#define NPAD 704
#define CHUNK 320
#define EPS_BN 1e-5f
#define LOG2E 1.4426950408889634f

#if __has_builtin(__builtin_amdgcn_exp2f)
#define EXP2(x) __builtin_amdgcn_exp2f(x)
#else
#define EXP2(x) exp2f(x)
#endif

typedef short short8 __attribute__((ext_vector_type(8)));
typedef float f32x4 __attribute__((ext_vector_type(4)));

// ---- ws layout (bytes) ----
#define XH_OFF 0
#define XL_OFF 2621440
#define WH_OFF 5242880
#define WL_OFF 8093696
#define PART_OFF 10944512
#define STATS_OFF 18153472
#define WS_NEED (STATS_OFF + 2 * NGRP * 8 * 4)

#define GLL16(g, l) __builtin_amdgcn_global_load_lds( \
    (const __attribute__((address_space(1))) void*)(g), \
    (__attribute__((address_space(3))) void*)(l), 16, 0, 0)

__device__ inline unsigned short bf16_rne(float x) {
    unsigned int u = __float_as_uint(x);
    return (unsigned short)((u + 0x7FFFu + ((u >> 16) & 1u)) >> 16);
}
__device__ inline float blo(unsigned int u) { return __uint_as_float(u << 16); }
__device__ inline float bhi(unsigned int u) { return __uint_as_float(u & 0xFFFF0000u); }

// ================== pre-split x,w into bf16 hi/lo arrays in ws ==================
__global__ __launch_bounds__(256) void split_kernel(const float* __restrict__ X,
                                                    const float* __restrict__ W,
                                                    unsigned short* __restrict__ ws) {
    const int NX4 = (BS * IN_CH) / 4;
    const int NW4 = (OUT_CH * IN_CH) / 4;
    int j = blockIdx.x * 256 + threadIdx.x;
    const float4* src;
    unsigned short *hi, *lo;
    int idx;
    if (j < NX4) {
        src = (const float4*)X; hi = ws + XH_OFF / 2; lo = ws + XL_OFF / 2; idx = j;
    } else if (j < NX4 + NW4) {
        src = (const float4*)W; hi = ws + WH_OFF / 2; lo = ws + WL_OFF / 2; idx = j - NX4;
    } else return;
    float4 v = src[idx];
    float f[4] = {v.x, v.y, v.z, v.w};
    unsigned short h[4], l[4];
#pragma unroll
    for (int i = 0; i < 4; ++i) {
        h[i] = bf16_rne(f[i]);
        float hf = __uint_as_float(((unsigned int)h[i]) << 16);
        l[i] = bf16_rne(f[i] - hf);
    }
    *(ushort4*)(hi + (size_t)idx * 4) = make_ushort4(h[0], h[1], h[2], h[3]);
    *(ushort4*)(lo + (size_t)idx * 4) = make_ushort4(l[0], l[1], l[2], l[3]);
}

// ================== MFMA GEMM: partial[z] = x@w^T (K-slice z) ===================
__global__ __launch_bounds__(256) void gemm_mfma(const unsigned short* __restrict__ wsu,
                                                 float* __restrict__ part) {
    __shared__ unsigned short Ah[4096], Al[4096], Bh[4096], Bl[4096];
    const unsigned short* XH = wsu + XH_OFF / 2;
    const unsigned short* XL = wsu + XL_OFF / 2;
    const unsigned short* WH = wsu + WH_OFF / 2;
    const unsigned short* WL = wsu + WL_OFF / 2;
    int tid = threadIdx.x;
    int w = tid >> 6, lane = tid & 63;
    int row0 = blockIdx.x * 64, col0 = blockIdx.y * 64;
    int k0 = blockIdx.z * (IN_CH / 4);

    int lr8 = lane >> 3;
    int sc = ((lane & 7) ^ lr8) << 3;
    int r0s = 16 * w + lr8;
    int arow0 = row0 + r0s, arow1 = arow0 + 8;
    int b0 = col0 + r0s;     if (b0 > OUT_CH - 1) b0 = OUT_CH - 1;
    int b1 = col0 + r0s + 8; if (b1 > OUT_CH - 1) b1 = OUT_CH - 1;
    const unsigned short* xh0 = XH + (size_t)arow0 * IN_CH + k0 + sc;
    const unsigned short* xh1 = XH + (size_t)arow1 * IN_CH + k0 + sc;
    const unsigned short* xl0 = XL + (size_t)arow0 * IN_CH + k0 + sc;
    const unsigned short* xl1 = XL + (size_t)arow1 * IN_CH + k0 + sc;
    const unsigned short* wh0 = WH + (size_t)b0 * IN_CH + k0 + sc;
    const unsigned short* wh1 = WH + (size_t)b1 * IN_CH + k0 + sc;
    const unsigned short* wl0 = WL + (size_t)b0 * IN_CH + k0 + sc;
    const unsigned short* wl1 = WL + (size_t)b1 * IN_CH + k0 + sc;
    int ldsA0 = (16 * w + 0) * 64;
    int ldsA1 = (16 * w + 8) * 64;

    int lr = lane & 15, lq = lane >> 4;
    int wr = (w >> 1) * 32, wc = (w & 1) * 32;
    f32x4 acc[2][2] = {};

    for (int kt = 0; kt < IN_CH / 4; kt += 64) {
        __syncthreads();
        GLL16(xh0 + kt, &Ah[ldsA0]);
        GLL16(xh1 + kt, &Ah[ldsA1]);
        GLL16(xl0 + kt, &Al[ldsA0]);
        GLL16(xl1 + kt, &Al[ldsA1]);
        GLL16(wh0 + kt, &Bh[ldsA0]);
        GLL16(wh1 + kt, &Bh[ldsA1]);
        GLL16(wl0 + kt, &Bl[ldsA0]);
        GLL16(wl1 + kt, &Bl[ldsA1]);
        __syncthreads();
#pragma unroll
        for (int kk2 = 0; kk2 < 2; ++kk2) {
            int ci = (kk2 << 2) + lq;
            short8 ahf[2], alf[2], bhf[2], blf[2];
#pragma unroll
            for (int mf = 0; mf < 2; ++mf) {
                int ra = wr + mf * 16 + lr;
                int ia = ra * 64 + ((ci ^ (ra & 7)) << 3);
                ahf[mf] = *(const short8*)&Ah[ia];
                alf[mf] = *(const short8*)&Al[ia];
                int rb = wc + mf * 16 + lr;
                int ib = rb * 64 + ((ci ^ (rb & 7)) << 3);
                bhf[mf] = *(const short8*)&Bh[ib];
                blf[mf] = *(const short8*)&Bl[ib];
            }
#pragma unroll
            for (int mf = 0; mf < 2; ++mf)
#pragma unroll
                for (int nf = 0; nf < 2; ++nf) {
                    acc[mf][nf] = __builtin_amdgcn_mfma_f32_16x16x32_bf16(ahf[mf], bhf[nf], acc[mf][nf], 0, 0, 0);
                    acc[mf][nf] = __builtin_amdgcn_mfma_f32_16x16x32_bf16(ahf[mf], blf[nf], acc[mf][nf], 0, 0, 0);
                    acc[mf][nf] = __builtin_amdgcn_mfma_f32_16x16x32_bf16(alf[mf], bhf[nf], acc[mf][nf], 0, 0, 0);
                }
        }
    }
    size_t zb = (size_t)blockIdx.z * BS;
#pragma unroll
    for (int mf = 0; mf < 2; ++mf)
#pragma unroll
        for (int nf = 0; nf < 2; ++nf)
#pragma unroll
            for (int j = 0; j < 4; ++j) {
                int r = row0 + wr + mf * 16 + lq * 4 + j;
                int c = col0 + wc + nf * 16 + lr;
                part[(zb + r) * NPAD + c] = acc[mf][nf][j];
            }
}

// ============== reduce split-K partials -> H, plus GhostBN folded stats =========
// stats layout: [(chunk*NGRP + n)*8 + {0..3: scale, 4..7: shift}]
__global__ __launch_bounds__(320) void stats_reduce(const float* __restrict__ part,
        float* __restrict__ H,
        const float* __restrict__ gamma, const float* __restrict__ beta,
        float* __restrict__ stats) {
    __shared__ float red[5][8];
    int n = blockIdx.x, chunk = blockIdx.y, tid = threadIdx.x;
    int c0 = n * 4;
    int l = chunk * CHUNK + tid;
    float4 a = *(const float4*)&part[((size_t)0 * BS + l) * NPAD + c0];
    float4 b = *(const float4*)&part[((size_t)1 * BS + l) * NPAD + c0];
    float4 c = *(const float4*)&part[((size_t)2 * BS + l) * NPAD + c0];
    float4 d = *(const float4*)&part[((size_t)3 * BS + l) * NPAD + c0];
    float hr[4] = {a.x + b.x + c.x + d.x, a.y + b.y + c.y + d.y,
                   a.z + b.z + c.z + d.z, a.w + b.w + c.w + d.w};
    *(float4*)&H[(size_t)l * OUT_CH + c0] = make_float4(hr[0], hr[1], hr[2], hr[3]);
    float rv[8];
#pragma unroll
    for (int e = 0; e < 4; ++e) { rv[e] = hr[e]; rv[4 + e] = hr[e] * hr[e]; }
#pragma unroll
    for (int off = 32; off > 0; off >>= 1)
#pragma unroll
        for (int j = 0; j < 8; ++j) rv[j] += __shfl_down(rv[j], off);
    int wv = tid >> 6, ln = tid & 63;
    if (ln == 0)
#pragma unroll
        for (int j = 0; j < 8; ++j) red[wv][j] = rv[j];
    __syncthreads();
    if (tid < 4) {
        int e = tid;
        float s = red[0][e] + red[1][e] + red[2][e] + red[3][e] + red[4][e];
        float ss = red[0][4 + e] + red[1][4 + e] + red[2][4 + e] + red[3][4 + e] + red[4][4 + e];
        float m = s * (1.0f / CHUNK);
        float var = ss * (1.0f / CHUNK) - m * m;
        float scv = rsqrtf(var + EPS_BN) * gamma[c0 + e];
        int j = chunk * NGRP + n;
        stats[j * 8 + e] = scv;
        stats[j * 8 + 4 + e] = beta[c0 + e] - m * scv;
    }
}

// ================== fallback path (small ws): round-2 kernels ===================
__global__ __launch_bounds__(256) void zero_kernel(float4* __restrict__ p, int n4) {
    int i = blockIdx.x * 256 + threadIdx.x;
    if (i < n4) p[i] = make_float4(0.f, 0.f, 0.f, 0.f);
}

__global__ __launch_bounds__(256) void gemm_fb(const float* __restrict__ X,
                                               const float* __restrict__ W,
                                               float* __restrict__ H) {
    __shared__ unsigned short Ah[64][72], Al[64][72], Bh[64][72], Bl[64][72];
    int tid = threadIdx.x;
    int row0 = blockIdx.x * 64;
    int col0 = blockIdx.y * 64;
    int k0 = blockIdx.z * (IN_CH / 4);
    int srow = tid >> 2;
    int skc = (tid & 3) * 16;
    const float* xp = X + (size_t)(row0 + srow) * IN_CH + k0 + skc;
    int wn = col0 + srow;
    const float* wp = W + (size_t)(wn < OUT_CH ? wn : 0) * IN_CH + k0 + skc;
    int w = tid >> 6;
    int lane = tid & 63;
    int wr = (w >> 1) * 32, wc = (w & 1) * 32;
    int lr = lane & 15, lq = lane >> 4;
    f32x4 acc[2][2] = {};
    for (int kt = 0; kt < IN_CH / 4; kt += 64) {
        float4 a[4], b[4];
#pragma unroll
        for (int i = 0; i < 4; ++i) {
            a[i] = *(const float4*)(xp + kt + 4 * i);
            b[i] = *(const float4*)(wp + kt + 4 * i);
        }
        __syncthreads();
#pragma unroll
        for (int i = 0; i < 4; ++i) {
            float av[4] = {a[i].x, a[i].y, a[i].z, a[i].w};
            float bv[4] = {b[i].x, b[i].y, b[i].z, b[i].w};
            unsigned short ah[4], al[4], bh[4], bl[4];
#pragma unroll
            for (int j = 0; j < 4; ++j) {
                ah[j] = bf16_rne(av[j]);
                al[j] = bf16_rne(av[j] - __uint_as_float(((unsigned int)ah[j]) << 16));
                bh[j] = bf16_rne(bv[j]);
                bl[j] = bf16_rne(bv[j] - __uint_as_float(((unsigned int)bh[j]) << 16));
            }
            *(ushort4*)&Ah[srow][skc + 4 * i] = make_ushort4(ah[0], ah[1], ah[2], ah[3]);
            *(ushort4*)&Al[srow][skc + 4 * i] = make_ushort4(al[0], al[1], al[2], al[3]);
            *(ushort4*)&Bh[srow][skc + 4 * i] = make_ushort4(bh[0], bh[1], bh[2], bh[3]);
            *(ushort4*)&Bl[srow][skc + 4 * i] = make_ushort4(bl[0], bl[1], bl[2], bl[3]);
        }
        __syncthreads();
#pragma unroll
        for (int kk = 0; kk < 64; kk += 32) {
            int ko = kk + lq * 8;
            short8 ahf[2], alf[2], bhf[2], blf[2];
#pragma unroll
            for (int mf = 0; mf < 2; ++mf) {
                ahf[mf] = *(const short8*)&Ah[wr + mf * 16 + lr][ko];
                alf[mf] = *(const short8*)&Al[wr + mf * 16 + lr][ko];
                bhf[mf] = *(const short8*)&Bh[wc + mf * 16 + lr][ko];
                blf[mf] = *(const short8*)&Bl[wc + mf * 16 + lr][ko];
            }
#pragma unroll
            for (int mf = 0; mf < 2; ++mf)
#pragma unroll
                for (int nf = 0; nf < 2; ++nf) {
                    acc[mf][nf] = __builtin_amdgcn_mfma_f32_16x16x32_bf16(ahf[mf], bhf[nf], acc[mf][nf], 0, 0, 0);
                    acc[mf][nf] = __builtin_amdgcn_mfma_f32_16x16x32_bf16(ahf[mf], blf[nf], acc[mf][nf], 0, 0, 0);
                    acc[mf][nf] = __builtin_amdgcn_mfma_f32_16x16x32_bf16(alf[mf], bhf[nf], acc[mf][nf], 0, 0, 0);
                }
        }
    }
#pragma unroll
    for (int mf = 0; mf < 2; ++mf)
#pragma unroll
        for (int nf = 0; nf < 2; ++nf)
#pragma unroll
            for (int j = 0; j < 4; ++j) {
                int r = row0 + wr + mf * 16 + lq * 4 + j;
                int c = col0 + wc + nf * 16 + lr;
                if (c < OUT_CH) atomicAdd(&H[(size_t)r * OUT_CH + c], acc[mf][nf][j]);
            }
}

__global__ __launch_bounds__(320) void stats_fb(const float* __restrict__ H,
        const float* __restrict__ gamma, const float* __restrict__ beta,
        float* __restrict__ stats) {
    __shared__ float red[5][8];
    int n = blockIdx.x, chunk = blockIdx.y, tid = threadIdx.x;
    int c0 = n * 4;
    int l = chunk * CHUNK + tid;
    float4 h4 = *(const float4*)(H + (size_t)l * OUT_CH + c0);
    float hr[4] = {h4.x, h4.y, h4.z, h4.w};
    float rv[8];
#pragma unroll
    for (int e = 0; e < 4; ++e) { rv[e] = hr[e]; rv[4 + e] = hr[e] * hr[e]; }
#pragma unroll
    for (int off = 32; off > 0; off >>= 1)
#pragma unroll
        for (int j = 0; j < 8; ++j) rv[j] += __shfl_down(rv[j], off);
    int wv = tid >> 6, ln = tid & 63;
    if (ln == 0)
#pragma unroll
        for (int j = 0; j < 8; ++j) red[wv][j] = rv[j];
    __syncthreads();
    if (tid < 4) {
        int e = tid;
        float s = red[0][e] + red[1][e] + red[2][e] + red[3][e] + red[4][e];
        float ss = red[0][4 + e] + red[1][4 + e] + red[2][4 + e] + red[3][4 + e] + red[4][4 + e];
        float m = s * (1.0f / CHUNK);
        float var = ss * (1.0f / CHUNK) - m * m;
        float scv = rsqrtf(var + EPS_BN) * gamma[c0 + e];
        int j = chunk * NGRP + n;
        stats[j * 8 + e] = scv;
        stats[j * 8 + 4 + e] = beta[c0 + e] - m * scv;
    }
}

// ========== attention v5: 32 queries/wave, Q=4/thread, seg=8 ====================
// grid (174, 10), block 128 (2 waves). Wave wv handles qb32 = blockIdx.y*2+wv.
// LDS kv staged once per block; slot t holds s = (t&7)*80 + (t>>3).
__global__ __launch_bounds__(128, 4) void attn_kernel(float* __restrict__ H,
        const float* __restrict__ prior,
        const float* __restrict__ stats,
        const float* __restrict__ ipw, const float* __restrict__ ipb,
        const float* __restrict__ opw, const float* __restrict__ opb) {
    __shared__ uint4 kv[BS];       // 10 KB
    __shared__ float kext[8];      // kmax[4], kmin[4]

    int n = blockIdx.x, tid = threadIdx.x;
    int lane = tid & 63, wv = tid >> 6;
    int c0 = n * 4;

    // ---- cooperative staging: project k,v from prior, pack bf16 ----
    for (int t = tid; t < BS; t += 128) {
        int s = (t & 7) * 80 + (t >> 3);
        float4 pr = *(const float4*)(prior + (size_t)s * OUT_CH + c0);
        float p_[4] = {pr.x, pr.y, pr.z, pr.w};
        float kk[4], vvv[4];
#pragma unroll
        for (int e = 0; e < 4; ++e) {
            float ak = ipb[4 + e], av = ipb[8 + e];
#pragma unroll
            for (int e2 = 0; e2 < 4; ++e2) {
                ak = fmaf(ipw[(4 + e) * 4 + e2], p_[e2], ak);
                av = fmaf(ipw[(8 + e) * 4 + e2], p_[e2], av);
            }
            kk[e] = ak; vvv[e] = av;
        }
        unsigned int u0 = (unsigned int)bf16_rne(kk[0]) | ((unsigned int)bf16_rne(kk[1]) << 16);
        unsigned int u1 = (unsigned int)bf16_rne(kk[2]) | ((unsigned int)bf16_rne(kk[3]) << 16);
        unsigned int u2 = (unsigned int)bf16_rne(vvv[0]) | ((unsigned int)bf16_rne(vvv[1]) << 16);
        unsigned int u3 = (unsigned int)bf16_rne(vvv[2]) | ((unsigned int)bf16_rne(vvv[3]) << 16);
        kv[t] = make_uint4(u0, u1, u2, u3);
    }
    __syncthreads();

    // ---- k extrema (wave 0), to LDS ----
    if (wv == 0) {
        float kmax[4] = {-3e38f, -3e38f, -3e38f, -3e38f};
        float kmin[4] = {3e38f, 3e38f, 3e38f, 3e38f};
        for (int t = lane; t < BS; t += 64) {
            uint4 u = kv[t];
            float k_[4] = {blo(u.x), bhi(u.x), blo(u.y), bhi(u.y)};
#pragma unroll
            for (int e = 0; e < 4; ++e) {
                kmax[e] = fmaxf(kmax[e], k_[e]);
                kmin[e] = fminf(kmin[e], k_[e]);
            }
        }
#pragma unroll
        for (int d = 32; d > 0; d >>= 1)
#pragma unroll
            for (int e = 0; e < 4; ++e) {
                kmax[e] = fmaxf(kmax[e], __shfl_xor(kmax[e], d));
                kmin[e] = fminf(kmin[e], __shfl_xor(kmin[e], d));
            }
        if (lane < 4) { kext[lane] = kmax[lane]; kext[4 + lane] = kmin[lane]; }
    }
    __syncthreads();

    int qb32 = blockIdx.y * 2 + wv;          // 0..19
    int qg = lane >> 3, seg = lane & 7;
    int q0 = qb32 * 32 + qg * 4;
    int chunk = (qb32 >= 10);
    int sj = (chunk * NGRP + n) * 8;
    float4 sc4 = *(const float4*)&stats[sj];
    float4 sh4 = *(const float4*)&stats[sj + 4];
    float scv[4] = {sc4.x, sc4.y, sc4.z, sc4.w};
    float shv[4] = {sh4.x, sh4.y, sh4.z, sh4.w};
    float km[4] = {kext[0], kext[1], kext[2], kext[3]};
    float kn[4] = {kext[4], kext[5], kext[6], kext[7]};

    // ---- per-thread q2 and stabilizer for 4 queries (hh recomputed later) ----
    float q2v[16], ntm[16];
#pragma unroll
    for (int qq = 0; qq < 4; ++qq) {
        float4 h4 = *(const float4*)(H + (size_t)(q0 + qq) * OUT_CH + c0);
        float4 p4 = *(const float4*)(prior + (size_t)(q0 + qq) * OUT_CH + c0);
        float hr[4] = {h4.x, h4.y, h4.z, h4.w};
        float pq[4] = {p4.x, p4.y, p4.z, p4.w};
        float hh[4];
#pragma unroll
        for (int e = 0; e < 4; ++e) hh[e] = fmaf(hr[e], scv[e], shv[e]) * pq[e];
#pragma unroll
        for (int e = 0; e < 4; ++e) {
            float qv = ipb[e];
#pragma unroll
            for (int e2 = 0; e2 < 4; ++e2) qv = fmaf(ipw[e * 4 + e2], hh[e2], qv);
            float q2 = qv * LOG2E;
            q2v[qq * 4 + e] = q2;
            ntm[qq * 4 + e] = -((q2 > 0.f) ? q2 * km[e] : q2 * kn[e]);
        }
    }

    // ---- 80-deep inner loop: 1 broadcast ds_read feeds 16 exps ----
    float ssum[16], sacc[16];
#pragma unroll
    for (int t2 = 0; t2 < 16; ++t2) { ssum[t2] = 0.f; sacc[t2] = 0.f; }
    const uint4* kp = kv + seg;
#pragma unroll 2
    for (int i = 0; i < 80; ++i) {
        uint4 u = kp[i * 8];
        float k0 = blo(u.x), k1 = bhi(u.x), k2 = blo(u.y), k3 = bhi(u.y);
        float v0 = blo(u.z), v1 = bhi(u.z), v2 = blo(u.w), v3 = bhi(u.w);
#pragma unroll
        for (int qq = 0; qq < 4; ++qq) {
            float w0 = EXP2(fmaf(q2v[qq * 4 + 0], k0, ntm[qq * 4 + 0]));
            float w1 = EXP2(fmaf(q2v[qq * 4 + 1], k1, ntm[qq * 4 + 1]));
            float w2 = EXP2(fmaf(q2v[qq * 4 + 2], k2, ntm[qq * 4 + 2]));
            float w3 = EXP2(fmaf(q2v[qq * 4 + 3], k3, ntm[qq * 4 + 3]));
            ssum[qq * 4 + 0] += w0; sacc[qq * 4 + 0] = fmaf(w0, v0, sacc[qq * 4 + 0]);
            ssum[qq * 4 + 1] += w1; sacc[qq * 4 + 1] = fmaf(w1, v1, sacc[qq * 4 + 1]);
            ssum[qq * 4 + 2] += w2; sacc[qq * 4 + 2] = fmaf(w2, v2, sacc[qq * 4 + 2]);
            ssum[qq * 4 + 3] += w3; sacc[qq * 4 + 3] = fmaf(w3, v3, sacc[qq * 4 + 3]);
        }
    }
    // ---- combine the 8 s-segments ----
#pragma unroll
    for (int d = 1; d < 8; d <<= 1)
#pragma unroll
        for (int t2 = 0; t2 < 16; ++t2) {
            ssum[t2] += __shfl_xor(ssum[t2], d);
            sacc[t2] += __shfl_xor(sacc[t2], d);
        }

    if (seg == 0) {
#pragma unroll
        for (int qq = 0; qq < 4; ++qq) {
            // recompute hh for this row (H row untouched: only this thread writes it)
            float4 h4 = *(const float4*)(H + (size_t)(q0 + qq) * OUT_CH + c0);
            float4 p4 = *(const float4*)(prior + (size_t)(q0 + qq) * OUT_CH + c0);
            float hr[4] = {h4.x, h4.y, h4.z, h4.w};
            float pq[4] = {p4.x, p4.y, p4.z, p4.w};
            float hh[4], o[4], y[4];
#pragma unroll
            for (int e = 0; e < 4; ++e) {
                hh[e] = fmaf(hr[e], scv[e], shv[e]) * pq[e];
                o[e] = sacc[qq * 4 + e] / ssum[qq * 4 + e];
            }
#pragma unroll
            for (int e = 0; e < 4; ++e) {
                float a = opb[e];
#pragma unroll
                for (int e2 = 0; e2 < 4; ++e2) a = fmaf(opw[e * 4 + e2], o[e2], a);
                y[e] = a;
            }
            *(float4*)(H + (size_t)(q0 + qq) * OUT_CH + c0) =
                make_float4(hh[0] + y[0], hh[1] + y[1], hh[2] + y[2], hh[3] + y[3]);
        }
    }
}

// ---------------- final row softmax over 696 channels, in-place ------------------
__global__ __launch_bounds__(256) void softmax_kernel(float* __restrict__ out) {
    __shared__ float red[4];
    int row = blockIdx.x;
    float* p = out + (size_t)row * OUT_CH;
    int tid = threadIdx.x;
    float v[3] = {-3e38f, -3e38f, -3e38f};
#pragma unroll
    for (int i = 0; i < 3; ++i) { int c = tid + i * 256; if (c < OUT_CH) v[i] = p[c]; }
    float mx = fmaxf(fmaxf(v[0], v[1]), v[2]);
#pragma unroll
    for (int off = 32; off > 0; off >>= 1) mx = fmaxf(mx, __shfl_down(mx, off));
    if ((tid & 63) == 0) red[tid >> 6] = mx;
    __syncthreads();
    mx = fmaxf(fmaxf(red[0], red[1]), fmaxf(red[2], red[3]));
    __syncthreads();
    float e[3] = {0.f, 0.f, 0.f};
    float s = 0.f;
#pragma unroll
    for (int i = 0; i < 3; ++i) {
        int c = tid + i * 256;
        if (c < OUT_CH) { e[i] = EXP2((v[i] - mx) * LOG2E); s += e[i]; }
    }
#pragma unroll
    for (int off = 32; off > 0; off >>= 1) s += __shfl_down(s, off);
    if ((tid & 63) == 0) red[tid >> 6] = s;
    __syncthreads();
    s = red[0] + red[1] + red[2] + red[3];
    float inv = 1.0f / s;
#pragma unroll
    for (int i = 0; i < 3; ++i) { int c = tid + i * 256; if (c < OUT_CH) p[c] = e[i] * inv; }
}

extern "C" void kernel_launch(void* const* d_in, const int* in_sizes, int n_in,
                              void* d_out, int out_size, void* d_ws, size_t ws_size,
                              hipStream_t stream) {
    const float* x     = (const float*)d_in[0];
    const float* prior = (const float*)d_in[1];
    const float* w_lin = (const float*)d_in[2];
    const float* gamma = (const float*)d_in[3];
    const float* beta  = (const float*)d_in[4];
    const float* ipw   = (const float*)d_in[5];
    const float* ipb   = (const float*)d_in[6];
    const float* opw   = (const float*)d_in[7];
    const float* opb   = (const float*)d_in[8];
    float* out = (float*)d_out;

    if (ws_size >= (size_t)WS_NEED) {
        unsigned short* wsu = (unsigned short*)d_ws;
        float* part  = (float*)((char*)d_ws + PART_OFF);
        float* stats = (float*)((char*)d_ws + STATS_OFF);
        const int NJOB = (BS * IN_CH) / 4 + (OUT_CH * IN_CH) / 4;
        split_kernel<<<NJOB / 256, 256, 0, stream>>>(x, w_lin, wsu);
        gemm_mfma<<<dim3(10, 11, 4), 256, 0, stream>>>(wsu, part);
        stats_reduce<<<dim3(NGRP, 2), 320, 0, stream>>>(part, out, gamma, beta, stats);
        attn_kernel<<<dim3(NGRP, 10), 128, 0, stream>>>(out, prior, stats, ipw, ipb, opw, opb);
        softmax_kernel<<<BS, 256, 0, stream>>>(out);
    } else {
        float* stats = (float*)d_ws;
        int n4 = (BS * OUT_CH) / 4;
        zero_kernel<<<(n4 + 255) / 256, 256, 0, stream>>>((float4*)out, n4);
        gemm_fb<<<dim3(10, 11, 4), 256, 0, stream>>>(x, w_lin, out);
        stats_fb<<<dim3(NGRP, 2), 320, 0, stream>>>(out, gamma, beta, stats);
        attn_kernel<<<dim3(NGRP, 10), 128, 0, stream>>>(out, prior, stats, ipw, ipb, opw, opb);
        softmax_kernel<<<BS, 256, 0, stream>>>(out);
    }
}